// Round 2
// baseline (142729.578 us; speedup 1.0000x reference)
//
#include <hip/hip_runtime.h>
#include <math.h>

#define BB 128
#define TT 256
#define HH 512
#define VV 32
#define MLEN 128
#define SLOT 65536  // HH*BB floats

// LDS float offsets (union across phases); wtile [256][65] at 0
#define MOFF 16640
#define LOFF 17152
#define COFF 17664
#define ROFF 19712
#define SMSZ 19776

struct P {
    const float *x, *emb;
    const float *eWih0, *eWhh0, *ebih0, *ebhh0;
    const float *eWih1, *eWhh1, *ebih1, *ebhh1;
    const float *dWih0, *dWhh0, *dbih0, *dbhh0;
    const float *dWih1, *dWhh1, *dbih1, *dbhh1;
    const float *qW, *qb, *outW, *outb;
    float *ws;
    float *vecO, *hidO, *attnO;
};

__device__ __forceinline__ float sigf(float v) { return 1.0f / (1.0f + __expf(-v)); }

// fast grid barrier: cnt at ws[0], gen at ws[32] (separate 128B lines), 256 blocks
__device__ __forceinline__ void gbar(int* cnt, int* gen) {
    __syncthreads();  // drains all block's vmem (compiler emits vmcnt(0) before s_barrier)
    if (threadIdx.x == 0) {
        __threadfence();
        int g = __hip_atomic_load(gen, __ATOMIC_RELAXED, __HIP_MEMORY_SCOPE_AGENT);
        if (__hip_atomic_fetch_add(cnt, 1, __ATOMIC_ACQ_REL, __HIP_MEMORY_SCOPE_AGENT) == 255) {
            __hip_atomic_store(cnt, 0, __ATOMIC_RELAXED, __HIP_MEMORY_SCOPE_AGENT);
            __hip_atomic_store(gen, g + 1, __ATOMIC_RELEASE, __HIP_MEMORY_SCOPE_AGENT);
        } else {
            while (__hip_atomic_load(gen, __ATOMIC_ACQUIRE, __HIP_MEMORY_SCOPE_AGENT) == g)
                __builtin_amdgcn_s_sleep(1);
        }
        __threadfence();
    }
    __syncthreads();
}

__global__ __launch_bounds__(512, 2) void kmain(P p) {
    const int tid = threadIdx.x;
    const int lane = tid & 63;
    const int wv = tid >> 6;
    const int blk = blockIdx.x;

    int* bcnt = (int*)p.ws;
    int* bgen = (int*)p.ws + 32;
    int* tok  = (int*)p.ws + 64;
    float* base = p.ws + 256;
    float* eh0 = base;                 // 2 slots (also decoder g0/h0)
    float* eh1 = base + 2 * SLOT;      // 2 slots (also decoder g1/h1)
    float* inp = base + 4 * SLOT;      // [1024][128]: embT rows 0..511, ctx rows 512..1023
    float* qbm = base + 6 * SLOT;      // [512][128]
    float* scoresB = base + 7 * SLOT;  // [256][128]
    float* embS = scoresB + TT * BB;   // [512][32]  emb transposed
    float* oWT  = embS + HH * VV;      // [128][32][4] outW packed for float4 loads
    float* encO = base + 8 * SLOT;     // [256 t][512 j][128 b]

    __shared__ float sm[SMSZ];

    // ---------------- init: zero enc h slots, build embS / oWT ----------------
    if (blk < 32) {
        float* dst = eh0 + SLOT;
        for (int i = blk * 512 + tid; i < SLOT; i += 32 * 512) dst[i] = 0.0f;
    } else if (blk < 64) {
        float* dst = eh1;
        for (int i = (blk - 32) * 512 + tid; i < SLOT; i += 32 * 512) dst[i] = 0.0f;
    } else if (blk < 96) {
        int idx = (blk - 64) * 512 + tid;          // 16384
        int d = idx >> 5, v = idx & 31;
        embS[idx] = p.emb[(size_t)v * HH + d];
    } else if (blk < 104) {
        int idx = (blk - 96) * 512 + tid;          // 4096 float4s
        int d4 = idx >> 5, v = idx & 31;
        float4 w = *(const float4*)(p.outW + (size_t)v * HH + d4 * 4);
        *(float4*)(oWT + (size_t)idx * 4) = w;
    }
    gbar(bcnt, bgen);

    // ---------------- encoder: 257 pipelined steps ----------------
    const int jgE = blk >> 1, bhE = blk & 1;
    const int jlE = wv & 3, dhE = wv >> 2;
    const int b64 = bhE * 64 + lane;

    for (int t = 0; t <= TT; ++t) {
        const float* h0s = eh0 + (((t + 1) & 1) ? SLOT : 0);
        float*       h0d = eh0 + ((t & 1) ? SLOT : 0);
        const float* h1s = eh1 + (((t + 1) & 1) ? SLOT : 0);
        float*       h1d = eh1 + ((t & 1) ? SLOT : 0);
        {
            const int j = __builtin_amdgcn_readfirstlane(jgE * 4 + jlE);
            const int d0 = dhE * 256;
            const float* w0r = p.eWhh0 + (size_t)j * HH + d0;
            const float* w0z = p.eWhh0 + (size_t)(j + HH) * HH + d0;
            const float* w0n = p.eWhh0 + (size_t)(j + 2 * HH) * HH + d0;
            const float* w1ir = p.eWih1 + (size_t)j * HH + d0;
            const float* w1iz = p.eWih1 + (size_t)(j + HH) * HH + d0;
            const float* w1in = p.eWih1 + (size_t)(j + 2 * HH) * HH + d0;
            const float* w1hr = p.eWhh1 + (size_t)j * HH + d0;
            const float* w1hz = p.eWhh1 + (size_t)(j + HH) * HH + d0;
            const float* w1hn = p.eWhh1 + (size_t)(j + 2 * HH) * HH + d0;
            const float* a0p = h0s + (size_t)d0 * BB + b64;
            const float* a1p = h1s + (size_t)d0 * BB + b64;
            float s0=0,s1=0,s2=0,s3=0,s4=0,s5=0,s6=0,s7=0,s8=0;
#pragma unroll 8
            for (int d = 0; d < 256; ++d) {
                float a = a0p[(size_t)d * BB];
                s0 = fmaf(w0r[d], a, s0); s1 = fmaf(w0z[d], a, s1); s2 = fmaf(w0n[d], a, s2);
                s3 = fmaf(w1ir[d], a, s3); s4 = fmaf(w1iz[d], a, s4); s5 = fmaf(w1in[d], a, s5);
            }
#pragma unroll 8
            for (int d = 0; d < 256; ++d) {
                float a = a1p[(size_t)d * BB];
                s6 = fmaf(w1hr[d], a, s6); s7 = fmaf(w1hz[d], a, s7); s8 = fmaf(w1hn[d], a, s8);
            }
            float* pp = sm + wv * 9 * 64 + lane;
            pp[0] = s0; pp[64] = s1; pp[128] = s2; pp[192] = s3; pp[256] = s4;
            pp[320] = s5; pp[384] = s6; pp[448] = s7; pp[512] = s8;
        }
        __syncthreads();
        if (wv < 4) {
            const int j = __builtin_amdgcn_readfirstlane(jgE * 4 + wv);
            const float* q0 = sm + wv * 9 * 64 + lane;
            const float* q1 = sm + (wv + 4) * 9 * 64 + lane;
            float r0 = q0[0] + q1[0],     r1 = q0[64] + q1[64],   r2 = q0[128] + q1[128];
            float r3 = q0[192] + q1[192], r4 = q0[256] + q1[256], r5 = q0[320] + q1[320];
            float r6 = q0[384] + q1[384], r7 = q0[448] + q1[448], r8 = q0[512] + q1[512];
            if (t < TT) {  // layer0 step t
                float x0 = p.x[((size_t)b64 * TT + t) * 2];
                float x1 = p.x[((size_t)b64 * TT + t) * 2 + 1];
                float hr = r0 + p.ebhh0[j], hz = r1 + p.ebhh0[j + HH], hn = r2 + p.ebhh0[j + 2 * HH];
                float ir = fmaf(p.eWih0[j * 2 + 1], x1, fmaf(p.eWih0[j * 2], x0, p.ebih0[j]));
                float iz = fmaf(p.eWih0[(j + HH) * 2 + 1], x1, fmaf(p.eWih0[(j + HH) * 2], x0, p.ebih0[j + HH]));
                float in_ = fmaf(p.eWih0[(j + 2 * HH) * 2 + 1], x1, fmaf(p.eWih0[(j + 2 * HH) * 2], x0, p.ebih0[j + 2 * HH]));
                float r = sigf(ir + hr), z = sigf(iz + hz);
                float n = tanhf(in_ + r * hn);
                float hp = h0s[(size_t)j * BB + b64];
                h0d[(size_t)j * BB + b64] = (1.0f - z) * n + z * hp;
            }
            if (t >= 1) {  // layer1 step t-1
                float ir = r3 + p.ebih1[j], iz = r4 + p.ebih1[j + HH], in_ = r5 + p.ebih1[j + 2 * HH];
                float hr = r6 + p.ebhh1[j], hz = r7 + p.ebhh1[j + HH], hn = r8 + p.ebhh1[j + 2 * HH];
                float r = sigf(ir + hr), z = sigf(iz + hz);
                float n = tanhf(in_ + r * hn);
                float hp = h1s[(size_t)j * BB + b64];
                float hv = (1.0f - z) * n + z * hp;
                h1d[(size_t)j * BB + b64] = hv;
                encO[((size_t)(t - 1) * HH + j) * BB + b64] = hv;
            }
        }
        gbar(bcnt, bgen);
    }

    // ---------------- dec-init: query from enc h1 final (eh1 slot0), tok=0 ----------------
    {
        if (blk < 128) {
            const int j = __builtin_amdgcn_readfirstlane(blk * 4 + (wv & 3));
            const int bh = wv >> 2;
            const int b = bh * 64 + lane;
            const float* g1 = eh1;  // slot 0
            const float* w = p.qW + (size_t)j * HH;
            float acc = p.qb[j];
#pragma unroll 8
            for (int d = 0; d < HH; ++d) acc = fmaf(w[d], g1[(size_t)d * BB + b], acc);
            qbm[(size_t)j * BB + b] = acc;
        } else if (blk == 136) {
            if (tid < BB) tok[tid] = 0;
        }
        gbar(bcnt, bgen);
    }

    // ---------------- decoder: 128 steps x 5 phases ----------------
    for (int s = 0; s < MLEN; ++s) {
        // --- A1: scores (blocks 0..127) + embT fill (blocks 128..135) ---
        if (blk < 128) {
            const int tg = blk >> 1, bh = blk & 1;
            const int t = tg * 4 + (wv & 3);
            const int jh = wv >> 2;
            const int b = bh * 64 + lane;
            const float* Ep = encO + ((size_t)t * HH + jh * 256) * BB + b;
            const float* qp = qbm + (size_t)(jh * 256) * BB + b;
            float acc = 0.0f;
#pragma unroll 8
            for (int i = 0; i < 256; ++i)
                acc = fmaf(Ep[(size_t)i * BB], qp[(size_t)i * BB], acc);
            sm[wv * 64 + lane] = acc;
            __syncthreads();
            if (jh == 0)
                scoresB[(size_t)t * BB + b] = sm[wv * 64 + lane] + sm[(wv + 4) * 64 + lane];
        } else if (blk < 136) {
            const int w = (blk - 128) * 8 + wv;  // 0..63
            const int dg = w >> 1, bh = w & 1;
            const int b = bh * 64 + lane;
            const int tk = tok[b];
#pragma unroll
            for (int dd = 0; dd < 16; ++dd) {
                int d = dg * 16 + dd;
                inp[(size_t)d * BB + b] = embS[d * 32 + tk];
            }
        }
        gbar(bcnt, bgen);

        // --- A2: softmax + context (all 256 blocks; dg==0 blocks also write attnO) ---
        {
            const int dg = blk >> 1, bh = blk & 1;
            const int b = bh * 64 + lane;
            const int d0 = dg * 4;
            const int tq0 = wv * 32;
            float mp = -1e30f;
            for (int k = 0; k < 32; ++k)
                mp = fmaxf(mp, scoresB[(size_t)(tq0 + k) * BB + b]);
            sm[MOFF + wv * 64 + lane] = mp;
            __syncthreads();
            float m = sm[MOFF + lane];
#pragma unroll
            for (int u = 1; u < 8; ++u) m = fmaxf(m, sm[MOFF + u * 64 + lane]);
            float lp = 0.0f;
            for (int k = 0; k < 32; ++k) {
                float e = __expf(scoresB[(size_t)(tq0 + k) * BB + b] - m);
                sm[(tq0 + k) * 65 + lane] = e;
                lp += e;
            }
            sm[LOFF + wv * 64 + lane] = lp;
            __syncthreads();
            float l = sm[LOFF + lane];
#pragma unroll
            for (int u = 1; u < 8; ++u) l += sm[LOFF + u * 64 + lane];
            float rl = 1.0f / l;
            if (wv == 0) sm[ROFF + lane] = rl;
            float c0 = 0, c1 = 0, c2 = 0, c3 = 0;
            for (int k = 0; k < 32; ++k) {
                int t = tq0 + k;
                float e = sm[t * 65 + lane];
                const float* Ep = encO + ((size_t)t * HH + d0) * BB + b;
                c0 = fmaf(e, Ep[0], c0);
                c1 = fmaf(e, Ep[BB], c1);
                c2 = fmaf(e, Ep[2 * BB], c2);
                c3 = fmaf(e, Ep[3 * BB], c3);
            }
            sm[COFF + (wv * 4 + 0) * 64 + lane] = c0;
            sm[COFF + (wv * 4 + 1) * 64 + lane] = c1;
            sm[COFF + (wv * 4 + 2) * 64 + lane] = c2;
            sm[COFF + (wv * 4 + 3) * 64 + lane] = c3;
            __syncthreads();
            if (tid < 256) {
                int k = tid >> 6, ln = tid & 63;
                float tot = 0.0f;
#pragma unroll
                for (int u = 0; u < 8; ++u) tot += sm[COFF + (u * 4 + k) * 64 + ln];
                tot *= sm[ROFF + ln];
                inp[(size_t)(HH + d0 + k) * BB + bh * 64 + ln] = tot;
            }
            if (dg == 0) {
                for (int r = 0; r < 32; ++r) {
                    int f = r * 512 + tid;
                    int bi = f >> 8, ti = f & 255;
                    float v = sm[ti * 65 + bi] * sm[ROFF + bi];
                    p.attnO[(((size_t)(bh * 64 + bi)) * MLEN + s) * TT + ti] = v;
                }
            }
        }
        gbar(bcnt, bgen);

        // --- G0: decoder gru layer0 ---
        {
            const int jg = blk >> 1, bh = blk & 1;
            const int jl = wv & 3, kh = wv >> 2;
            const int j = __builtin_amdgcn_readfirstlane(jg * 4 + jl);
            const int b = bh * 64 + lane;
            const float* h0s = eh0 + (((s + 1) & 1) ? SLOT : 0);
            float* g0d = eh0 + ((s & 1) ? SLOT : 0);
            const float* wir = p.dWih0 + (size_t)j * 1024;
            const float* wiz = p.dWih0 + (size_t)(j + HH) * 1024;
            const float* win = p.dWih0 + (size_t)(j + 2 * HH) * 1024;
            float pir = 0, piz = 0, pin = 0, par = 0, paz = 0, pan = 0;
            if (kh == 0) {
                const float* ap = inp + b;
#pragma unroll 8
                for (int c = 0; c < 768; ++c) {
                    float a = ap[(size_t)c * BB];
                    pir = fmaf(wir[c], a, pir); piz = fmaf(wiz[c], a, piz); pin = fmaf(win[c], a, pin);
                }
            } else {
                const float* ap = inp + (size_t)768 * BB + b;
#pragma unroll 8
                for (int c = 0; c < 256; ++c) {
                    float a = ap[(size_t)c * BB];
                    pir = fmaf(wir[768 + c], a, pir); piz = fmaf(wiz[768 + c], a, piz); pin = fmaf(win[768 + c], a, pin);
                }
                const float* whr = p.dWhh0 + (size_t)j * HH;
                const float* whz = p.dWhh0 + (size_t)(j + HH) * HH;
                const float* whn = p.dWhh0 + (size_t)(j + 2 * HH) * HH;
                const float* hp = h0s + b;
#pragma unroll 8
                for (int d = 0; d < HH; ++d) {
                    float a = hp[(size_t)d * BB];
                    par = fmaf(whr[d], a, par); paz = fmaf(whz[d], a, paz); pan = fmaf(whn[d], a, pan);
                }
            }
            float* pp = sm + wv * 6 * 64 + lane;
            pp[0] = pir; pp[64] = piz; pp[128] = pin; pp[192] = par; pp[256] = paz; pp[320] = pan;
            __syncthreads();
            if (wv < 4) {
                const int jj = __builtin_amdgcn_readfirstlane(jg * 4 + wv);
                const float* q0 = sm + wv * 6 * 64 + lane;
                const float* q1 = sm + (wv + 4) * 6 * 64 + lane;
                float ir = q0[0] + q1[0] + p.dbih0[jj];
                float iz = q0[64] + q1[64] + p.dbih0[jj + HH];
                float in_ = q0[128] + q1[128] + p.dbih0[jj + 2 * HH];
                float hr = q0[192] + q1[192] + p.dbhh0[jj];
                float hz = q0[256] + q1[256] + p.dbhh0[jj + HH];
                float hn = q0[320] + q1[320] + p.dbhh0[jj + 2 * HH];
                float r = sigf(ir + hr), z = sigf(iz + hz);
                float n = tanhf(in_ + r * hn);
                float hp = h0s[(size_t)jj * BB + b];
                g0d[(size_t)jj * BB + b] = (1.0f - z) * n + z * hp;
            }
        }
        gbar(bcnt, bgen);

        // --- G1: decoder gru layer1 ---
        {
            const int jg = blk >> 1, bh = blk & 1;
            const int jl = wv & 3, dh = wv >> 2;
            const int j = __builtin_amdgcn_readfirstlane(jg * 4 + jl);
            const int b = bh * 64 + lane;
            const float* g0 = eh0 + ((s & 1) ? SLOT : 0);
            const float* h1s = eh1 + ((s & 1) ? SLOT : 0);
            float* h1d = eh1 + (((s + 1) & 1) ? SLOT : 0);
            const int d0 = dh * 256;
            const float* wir = p.dWih1 + (size_t)j * HH + d0;
            const float* wiz = p.dWih1 + (size_t)(j + HH) * HH + d0;
            const float* win = p.dWih1 + (size_t)(j + 2 * HH) * HH + d0;
            const float* whr = p.dWhh1 + (size_t)j * HH + d0;
            const float* whz = p.dWhh1 + (size_t)(j + HH) * HH + d0;
            const float* whn = p.dWhh1 + (size_t)(j + 2 * HH) * HH + d0;
            const float* ai = g0 + (size_t)d0 * BB + b;
            const float* ah = h1s + (size_t)d0 * BB + b;
            float pir = 0, piz = 0, pin = 0, par = 0, paz = 0, pan = 0;
#pragma unroll 8
            for (int d = 0; d < 256; ++d) {
                float a = ai[(size_t)d * BB];
                pir = fmaf(wir[d], a, pir); piz = fmaf(wiz[d], a, piz); pin = fmaf(win[d], a, pin);
            }
#pragma unroll 8
            for (int d = 0; d < 256; ++d) {
                float a = ah[(size_t)d * BB];
                par = fmaf(whr[d], a, par); paz = fmaf(whz[d], a, paz); pan = fmaf(whn[d], a, pan);
            }
            float* pp = sm + wv * 6 * 64 + lane;
            pp[0] = pir; pp[64] = piz; pp[128] = pin; pp[192] = par; pp[256] = paz; pp[320] = pan;
            __syncthreads();
            if (wv < 4) {
                const int jj = __builtin_amdgcn_readfirstlane(jg * 4 + wv);
                const float* q0 = sm + wv * 6 * 64 + lane;
                const float* q1 = sm + (wv + 4) * 6 * 64 + lane;
                float ir = q0[0] + q1[0] + p.dbih1[jj];
                float iz = q0[64] + q1[64] + p.dbih1[jj + HH];
                float in_ = q0[128] + q1[128] + p.dbih1[jj + 2 * HH];
                float hr = q0[192] + q1[192] + p.dbhh1[jj];
                float hz = q0[256] + q1[256] + p.dbhh1[jj + HH];
                float hn = q0[320] + q1[320] + p.dbhh1[jj + 2 * HH];
                float r = sigf(ir + hr), z = sigf(iz + hz);
                float n = tanhf(in_ + r * hn);
                float hp = h1s[(size_t)jj * BB + b];
                h1d[(size_t)jj * BB + b] = (1.0f - z) * n + z * hp;
            }
        }
        gbar(bcnt, bgen);

        // --- D: query (blocks 0..127) + logits/argmax/tok/vecO (blocks 128..135) ---
        {
            const float* g1 = eh1 + (((s + 1) & 1) ? SLOT : 0);
            if (blk < 128) {
                const int j = __builtin_amdgcn_readfirstlane(blk * 4 + (wv & 3));
                const int bh = wv >> 2;
                const int b = bh * 64 + lane;
                const float* w = p.qW + (size_t)j * HH;
                float acc = p.qb[j];
#pragma unroll 8
                for (int d = 0; d < HH; ++d) acc = fmaf(w[d], g1[(size_t)d * BB + b], acc);
                qbm[(size_t)j * BB + b] = acc;
            } else if (blk < 136) {
                const int w = (blk - 128) * 8 + wv;  // 0..63
                const int v = lane & 31, b2 = lane >> 5;
                const int b = w * 2 + b2;
                const float4* wp = (const float4*)oWT;
                float acc = 0.0f;
#pragma unroll 4
                for (int d4 = 0; d4 < 128; ++d4) {
                    float4 wl = wp[d4 * 32 + v];
                    acc = fmaf(wl.x, g1[(size_t)(d4 * 4 + 0) * BB + b], acc);
                    acc = fmaf(wl.y, g1[(size_t)(d4 * 4 + 1) * BB + b], acc);
                    acc = fmaf(wl.z, g1[(size_t)(d4 * 4 + 2) * BB + b], acc);
                    acc = fmaf(wl.w, g1[(size_t)(d4 * 4 + 3) * BB + b], acc);
                }
                acc += p.outb[v];
                p.vecO[((size_t)b * MLEN + s) * VV + v] = acc;
                sm[wv * 64 + lane] = acc;
                if (v == 0) {  // wave-local scan: jnp.argmax first-max semantics
                    float best = sm[wv * 64 + b2 * 32];
                    int bi = 0;
                    for (int u = 1; u < 32; ++u) {
                        float val = sm[wv * 64 + b2 * 32 + u];
                        if (val > best) { best = val; bi = u; }
                    }
                    tok[b] = bi;
                }
            }
        }
        gbar(bcnt, bgen);
    }

    // ---------------- final hidden: [l][b][h] from d-major slots ----------------
    {
        int idx = blk * 512 + tid;  // 0..131071 exactly
        int l = idx >> 16, rr = idx & 65535;
        int b = rr >> 9, h = rr & 511;
        const float* src = l ? eh1 : (eh0 + SLOT);  // dh1 final slot0, dh0 final slot1
        p.hidO[idx] = src[(size_t)h * BB + b];
    }
}

extern "C" void kernel_launch(void* const* d_in, const int* in_sizes, int n_in,
                              void* d_out, int out_size, void* d_ws, size_t ws_size,
                              hipStream_t stream) {
    (void)in_sizes; (void)n_in; (void)out_size; (void)ws_size;
    P prm;
    prm.x     = (const float*)d_in[0];
    prm.emb   = (const float*)d_in[1];
    prm.eWih0 = (const float*)d_in[2];
    prm.eWhh0 = (const float*)d_in[3];
    prm.ebih0 = (const float*)d_in[4];
    prm.ebhh0 = (const float*)d_in[5];
    prm.eWih1 = (const float*)d_in[6];
    prm.eWhh1 = (const float*)d_in[7];
    prm.ebih1 = (const float*)d_in[8];
    prm.ebhh1 = (const float*)d_in[9];
    prm.dWih0 = (const float*)d_in[10];
    prm.dWhh0 = (const float*)d_in[11];
    prm.dbih0 = (const float*)d_in[12];
    prm.dbhh0 = (const float*)d_in[13];
    prm.dWih1 = (const float*)d_in[14];
    prm.dWhh1 = (const float*)d_in[15];
    prm.dbih1 = (const float*)d_in[16];
    prm.dbhh1 = (const float*)d_in[17];
    prm.qW    = (const float*)d_in[18];
    prm.qb    = (const float*)d_in[19];
    prm.outW  = (const float*)d_in[20];
    prm.outb  = (const float*)d_in[21];
    prm.ws    = (float*)d_ws;
    prm.vecO  = (float*)d_out;
    prm.hidO  = prm.vecO + (size_t)BB * MLEN * VV;
    prm.attnO = prm.hidO + (size_t)2 * BB * HH;

    hipMemsetAsync(d_ws, 0, 256, stream);  // barrier cnt/gen
    void* args[] = { &prm };
    hipLaunchCooperativeKernel((void*)kmain, dim3(256), dim3(512), args, 0, stream);
}

// Round 3
// 36258.548 us; speedup vs baseline: 3.9364x; 3.9364x over previous
//
#include <hip/hip_runtime.h>
#include <math.h>

#define BB 128
#define TT 256
#define HH 512
#define VV 32
#define MLEN 128
#define SLOT 65536          // HH*BB floats

// LDS layout (floats). Tile region @0 (12288), pR @12288 (1792 max), QTILE @14080 (2048).
#define PR_OFF 12288
#define QT_OFF 14080
#define SM_FLOATS 16128     // 64512 bytes

typedef long long ll;

struct P {
    const float *x, *emb;
    const float *eWih0, *eWhh0, *ebih0, *ebhh0;
    const float *eWih1, *eWhh1, *ebih1, *ebhh1;
    const float *dWih0, *dWhh0, *dbih0, *dbhh0;
    const float *dWih1, *dWhh1, *dbih1, *dbhh1;
    const float *qW, *qb, *outW, *outb;
    float *ws;
    float *vecO, *hidO, *attnO;
};

__device__ __forceinline__ float sigf(float v) { return 1.0f / (1.0f + __expf(-v)); }

// device-coherent (LLC) relaxed ops — no cache-maintenance side effects
__device__ __forceinline__ float ldA(const float* p) {
    return __hip_atomic_load(p, __ATOMIC_RELAXED, __HIP_MEMORY_SCOPE_AGENT);
}
__device__ __forceinline__ void stA(float* p, float v) {
    __hip_atomic_store(p, v, __ATOMIC_RELAXED, __HIP_MEMORY_SCOPE_AGENT);
}
__device__ __forceinline__ int ldAi(const int* p) {
    return __hip_atomic_load(p, __ATOMIC_RELAXED, __HIP_MEMORY_SCOPE_AGENT);
}
__device__ __forceinline__ void stAi(int* p, int v) {
    __hip_atomic_store(p, v, __ATOMIC_RELAXED, __HIP_MEMORY_SCOPE_AGENT);
}

// relaxed-only two-level grid barrier. gen @W[0]; group cnts parity-slotted
// @W[32 + (par*16+g)*32]; roots @W[1056 + par*32]. No fences: data ordering is
// vmcnt-drain (__syncthreads) before arrival + LLC-coherent data ops.
__device__ __forceinline__ void gbar(int* W, int target) {
    __syncthreads();
    if (threadIdx.x == 0) {
        int par = target & 1;
        int g = blockIdx.x & 15;
        int* gc = W + 32 + (par * 16 + g) * 32;
        if (__hip_atomic_fetch_add(gc, 1, __ATOMIC_RELAXED, __HIP_MEMORY_SCOPE_AGENT) == 15) {
            __hip_atomic_store(gc, 0, __ATOMIC_RELAXED, __HIP_MEMORY_SCOPE_AGENT);
            int* rc = W + 1056 + par * 32;
            if (__hip_atomic_fetch_add(rc, 1, __ATOMIC_RELAXED, __HIP_MEMORY_SCOPE_AGENT) == 15) {
                __hip_atomic_store(rc, 0, __ATOMIC_RELAXED, __HIP_MEMORY_SCOPE_AGENT);
                __hip_atomic_store(W, target, __ATOMIC_RELAXED, __HIP_MEMORY_SCOPE_AGENT);
            }
        }
        while (__hip_atomic_load(W, __ATOMIC_RELAXED, __HIP_MEMORY_SCOPE_AGENT) < target)
            __builtin_amdgcn_s_sleep(2);
    }
    __syncthreads();
}

__global__ __launch_bounds__(512, 2) void kmain(P p) {
    const int tid = threadIdx.x;
    const int lane = tid & 63;
    const int wv = tid >> 6;
    const int blk = blockIdx.x;

    int* W = (int*)p.ws;
    int* tok = W + 4096;
    float* f = (float*)p.ws + 8192;
    float* eh0 = f;                       // 2 slots
    float* eh1 = f + 2 * SLOT;            // 2 slots
    float* inp = f + 4 * SLOT;            // ctx [512 d][128 b]
    float* qbm = f + 5 * SLOT;            // [512 j][128 b]
    float* scoresB = f + 6 * SLOT;        // [256 t][128 b]
    float* T = f + 6 * SLOT + SLOT / 2;   // [3][512][32] emb-projection table
    float* xT = T + 3 * HH * VV;          // [256 t][2][128 b]
    float* encO = f + (SLOT / 4) * 33;    // [256 t][512 j][128 b]

    __shared__ float smu[SM_FLOATS];
    const float4* t4 = (const float4*)smu;
    const float4* t4q = (const float4*)(smu + QT_OFF);

    const int jg = blk >> 1;              // 0..127, owns j = 4*jg..4*jg+3
    const int bh = blk & 1;
    const int b2 = bh * 64 + lane;
    int bar = 0;

    // ================= INIT =================
    {
        // zero 4 h slots (262144 floats)
        stA(eh0 + blk * 1024 + tid, 0.0f);
        stA(eh0 + blk * 1024 + 512 + tid, 0.0f);
        // xT transpose (write-once via stA; later read cached)
        if (tid < 256) {
            int idx = blk * 256 + tid;
            int t = idx >> 8, c = (idx >> 7) & 1, b = idx & 127;
            stA(xT + idx, p.x[((ll)b * TT + t) * 2 + c]);
        }
        // T table: T[(g*512+j)*32+v] = dot(dWih0[g*512+j][0:512], emb[v])
        if (tid < 192) {
            int unit = blk * 192 + tid;
            int v = unit & 31, gj = unit >> 5;
            const float* wrow = p.dWih0 + (ll)gj * 1024;
            const float* erow = p.emb + (ll)v * HH;
            float acc = 0.0f;
#pragma unroll 8
            for (int d = 0; d < HH; ++d) acc = fmaf(wrow[d], erow[d], acc);
            stA(T + unit, acc);
        }
        // stage qW tile (persistent @QT_OFF)
#pragma unroll
        for (int jl = 0; jl < 4; ++jl)
            smu[QT_OFF + jl * 512 + tid] = p.qW[((ll)(jg * 4 + jl)) * HH + tid];
        gbar(W, ++bar);
    }

    // ================= ENCODER: 257 pipelined steps =================
    for (int t = 0; t <= TT; ++t) {
        const float* h0s = eh0 + (((t + 1) & 1) ? SLOT : 0);
        float*       h0d = eh0 + ((t & 1) ? SLOT : 0);
        const float* h1s = eh1 + (((t + 1) & 1) ? SLOT : 0);
        float*       h1d = eh1 + ((t & 1) ? SLOT : 0);

        // stage round-A tile: 24 rows (hr0,hz0,hn0,ir1,iz1,in1 x 4j) over d=0..511
#pragma unroll
        for (int r = 0; r < 24; ++r) {
            int g = r >> 2, jl = r & 3, j = jg * 4 + jl;
            const float* src = (g < 3) ? (p.eWhh0 + (ll)(g * HH + j) * HH)
                                       : (p.eWih1 + (ll)((g - 3) * HH + j) * HH);
            smu[r * 512 + tid] = src[tid];
        }
        smu[PR_OFF + tid] = 0.0f;
        smu[PR_OFF + 512 + tid] = 0.0f;
        smu[PR_OFF + 1024 + tid] = 0.0f;
        if (tid < 256) smu[PR_OFF + 1536 + tid] = 0.0f;
        __syncthreads();

        // round A: stream h0s (feeds l0 h-gates + l1 i-gates)
        {
            const int ds0 = wv * 64;
            float acc[24];
#pragma unroll
            for (int r = 0; r < 24; ++r) acc[r] = 0.0f;
            float av[8];
            for (int c = 0; c < 8; ++c) {
                int db = ds0 + c * 8;
#pragma unroll
                for (int u = 0; u < 8; ++u) av[u] = ldA(h0s + (ll)(db + u) * BB + b2);
#pragma unroll
                for (int h2 = 0; h2 < 2; ++h2) {
                    int q4 = (db + h2 * 4) >> 2;
#pragma unroll
                    for (int r = 0; r < 24; ++r) {
                        float4 w = t4[r * 128 + q4];
                        acc[r] = fmaf(w.x, av[h2 * 4 + 0], acc[r]);
                        acc[r] = fmaf(w.y, av[h2 * 4 + 1], acc[r]);
                        acc[r] = fmaf(w.z, av[h2 * 4 + 2], acc[r]);
                        acc[r] = fmaf(w.w, av[h2 * 4 + 3], acc[r]);
                    }
                }
            }
#pragma unroll
            for (int r = 0; r < 24; ++r)
                unsafeAtomicAdd(&smu[PR_OFF + r * 64 + lane], acc[r]);
        }
        __syncthreads();

        // stage round-B tile: 12 rows (hr1,hz1,hn1 x 4j)
#pragma unroll
        for (int r = 0; r < 12; ++r) {
            int g = r >> 2, jl = r & 3, j = jg * 4 + jl;
            smu[r * 512 + tid] = p.eWhh1[(ll)(g * HH + j) * HH + tid];
        }
        __syncthreads();

        // round B: stream h1s (l1 h-gates)
        {
            const int ds0 = wv * 64;
            float acc[12];
#pragma unroll
            for (int r = 0; r < 12; ++r) acc[r] = 0.0f;
            float av[8];
            for (int c = 0; c < 8; ++c) {
                int db = ds0 + c * 8;
#pragma unroll
                for (int u = 0; u < 8; ++u) av[u] = ldA(h1s + (ll)(db + u) * BB + b2);
#pragma unroll
                for (int h2 = 0; h2 < 2; ++h2) {
                    int q4 = (db + h2 * 4) >> 2;
#pragma unroll
                    for (int r = 0; r < 12; ++r) {
                        float4 w = t4[r * 128 + q4];
                        acc[r] = fmaf(w.x, av[h2 * 4 + 0], acc[r]);
                        acc[r] = fmaf(w.y, av[h2 * 4 + 1], acc[r]);
                        acc[r] = fmaf(w.z, av[h2 * 4 + 2], acc[r]);
                        acc[r] = fmaf(w.w, av[h2 * 4 + 3], acc[r]);
                    }
                }
            }
#pragma unroll
            for (int r = 0; r < 12; ++r) {
                int g = r >> 2;
                int prow = (g < 2) ? (12 + g * 4) : 24;
                unsafeAtomicAdd(&smu[PR_OFF + (prow + (r & 3)) * 64 + lane], acc[r]);
            }
        }
        __syncthreads();

        // finalize
        if (wv < 4) {
            int jl = wv, j = jg * 4 + jl;
            float* pr = smu + PR_OFF;
            if (t < TT) {
                float hr = pr[(0 + jl) * 64 + lane] + p.ebhh0[j];
                float hz = pr[(4 + jl) * 64 + lane] + p.ebhh0[HH + j];
                float hn = pr[(8 + jl) * 64 + lane] + p.ebhh0[2 * HH + j];
                float x0 = xT[t * 256 + b2], x1 = xT[t * 256 + 128 + b2];
                float ir = fmaf(p.eWih0[j * 2], x0, fmaf(p.eWih0[j * 2 + 1], x1, p.ebih0[j]));
                float iz = fmaf(p.eWih0[(HH + j) * 2], x0, fmaf(p.eWih0[(HH + j) * 2 + 1], x1, p.ebih0[HH + j]));
                float in_ = fmaf(p.eWih0[(2 * HH + j) * 2], x0, fmaf(p.eWih0[(2 * HH + j) * 2 + 1], x1, p.ebih0[2 * HH + j]));
                float r = sigf(ir + hr), z = sigf(iz + hz);
                float n = tanhf(in_ + r * hn);
                float hp = ldA(h0s + (ll)j * BB + b2);
                stA(h0d + (ll)j * BB + b2, (1.0f - z) * n + z * hp);
            }
            if (t >= 1) {
                float rs = pr[(12 + jl) * 64 + lane] + p.ebih1[j] + p.ebhh1[j];
                float zs = pr[(16 + jl) * 64 + lane] + p.ebih1[HH + j] + p.ebhh1[HH + j];
                float in1 = pr[(20 + jl) * 64 + lane] + p.ebih1[2 * HH + j];
                float hn1 = pr[(24 + jl) * 64 + lane] + p.ebhh1[2 * HH + j];
                float r = sigf(rs), z = sigf(zs);
                float n = tanhf(in1 + r * hn1);
                float hp = ldA(h1s + (ll)j * BB + b2);
                float hv = (1.0f - z) * n + z * hp;
                stA(h1d + (ll)j * BB + b2, hv);
                stA(encO + ((ll)(t - 1) * HH + j) * BB + b2, hv);
            }
        }
        gbar(W, ++bar);
    }

    // ================= DEC-INIT: query from enc h1 final (slot0), tok=0 =================
    {
        const float* h1c = eh1;  // slot 0
        if (tid < 256) smu[PR_OFF + tid] = 0.0f;
        __syncthreads();
        {
            const int ds0 = wv * 64;
            float acc[4] = {0, 0, 0, 0};
            float av[8];
            for (int c = 0; c < 8; ++c) {
                int db = ds0 + c * 8;
#pragma unroll
                for (int u = 0; u < 8; ++u) av[u] = ldA(h1c + (ll)(db + u) * BB + b2);
#pragma unroll
                for (int h2 = 0; h2 < 2; ++h2) {
                    int q4 = (db + h2 * 4) >> 2;
#pragma unroll
                    for (int jl = 0; jl < 4; ++jl) {
                        float4 w = t4q[jl * 128 + q4];
                        acc[jl] = fmaf(w.x, av[h2 * 4 + 0], acc[jl]);
                        acc[jl] = fmaf(w.y, av[h2 * 4 + 1], acc[jl]);
                        acc[jl] = fmaf(w.z, av[h2 * 4 + 2], acc[jl]);
                        acc[jl] = fmaf(w.w, av[h2 * 4 + 3], acc[jl]);
                    }
                }
            }
#pragma unroll
            for (int jl = 0; jl < 4; ++jl)
                unsafeAtomicAdd(&smu[PR_OFF + jl * 64 + lane], acc[jl]);
        }
        __syncthreads();
        if (wv < 4) {
            int j = jg * 4 + wv;
            stA(qbm + (ll)j * BB + b2, smu[PR_OFF + wv * 64 + lane] + p.qb[j]);
        }
        if (blk == 128 && tid < BB) stAi(tok + tid, 0);
        gbar(W, ++bar);
    }

    // ================= DECODER: 128 steps x 5 phases =================
    for (int s = 0; s < MLEN; ++s) {
        const float* h0s = eh0 + (((s + 1) & 1) ? SLOT : 0);
        float*       g0d = eh0 + ((s & 1) ? SLOT : 0);
        const float* h1s = eh1 + ((s & 1) ? SLOT : 0);
        float*       h1d = eh1 + (((s + 1) & 1) ? SLOT : 0);

        // --- A1: scores (blocks 0..127) ---
        if (blk < 128) {
            const int tq4 = jg * 4;  // jg here = t-quad index 0..63 when blk<128
            if (tid < 256) smu[PR_OFF + tid] = 0.0f;
            __syncthreads();
            const int js = wv * 64;
            float acc[4] = {0, 0, 0, 0};
            float qv[8];
            for (int c = 0; c < 8; ++c) {
#pragma unroll
                for (int u = 0; u < 8; ++u) qv[u] = ldA(qbm + (ll)(js + c * 8 + u) * BB + b2);
#pragma unroll
                for (int u = 0; u < 8; ++u) {
                    int jj = js + c * 8 + u;
#pragma unroll
                    for (int tt = 0; tt < 4; ++tt)
                        acc[tt] = fmaf(qv[u], encO[((ll)(tq4 + tt) * HH + jj) * BB + b2], acc[tt]);
                }
            }
#pragma unroll
            for (int tt = 0; tt < 4; ++tt)
                unsafeAtomicAdd(&smu[PR_OFF + tt * 64 + lane], acc[tt]);
            __syncthreads();
            if (wv < 4)
                stA(scoresB + (ll)(tq4 + wv) * BB + b2, smu[PR_OFF + wv * 64 + lane]);
        }
        gbar(W, ++bar);

        // --- A2: softmax + context (all 256 blocks); blocks<16 write attnO ---
        {
            const int d0 = jg * 4;  // ctx dims
            float sv[32];
#pragma unroll
            for (int k = 0; k < 32; ++k) sv[k] = ldA(scoresB + (ll)(wv * 32 + k) * BB + b2);
            if (tid < 256) smu[PR_OFF + tid] = 0.0f;
            float mp = sv[0];
#pragma unroll
            for (int k = 1; k < 32; ++k) mp = fmaxf(mp, sv[k]);
            smu[wv * 64 + lane] = mp;
            __syncthreads();
            float m = smu[lane];
#pragma unroll
            for (int u = 1; u < 8; ++u) m = fmaxf(m, smu[u * 64 + lane]);
            float e[32], lp = 0.0f;
#pragma unroll
            for (int k = 0; k < 32; ++k) { e[k] = __expf(sv[k] - m); lp += e[k]; }
            smu[512 + wv * 64 + lane] = lp;
            __syncthreads();
            float l = smu[512 + lane];
#pragma unroll
            for (int u = 1; u < 8; ++u) l += smu[512 + u * 64 + lane];
            float rl = 1.0f / l;
            if (blk < 16 && wv == jg) {
#pragma unroll
                for (int k = 0; k < 32; ++k) smu[2048 + k * 65 + lane] = e[k] * rl;
            }
            float c4[4] = {0, 0, 0, 0};
            for (int k = 0; k < 32; ++k) {
                int t = wv * 32 + k;
                const float* Ep = encO + ((ll)t * HH + d0) * BB + b2;
                c4[0] = fmaf(e[k], Ep[0], c4[0]);
                c4[1] = fmaf(e[k], Ep[BB], c4[1]);
                c4[2] = fmaf(e[k], Ep[2 * BB], c4[2]);
                c4[3] = fmaf(e[k], Ep[3 * BB], c4[3]);
            }
#pragma unroll
            for (int kk = 0; kk < 4; ++kk)
                unsafeAtomicAdd(&smu[PR_OFF + kk * 64 + lane], c4[kk]);
            __syncthreads();
            if (tid < 256) {
                int kk = tid >> 6, ln = tid & 63;
                float l2 = smu[512 + ln];
#pragma unroll
                for (int u = 1; u < 8; ++u) l2 += smu[512 + u * 64 + ln];
                float val = smu[PR_OFF + kk * 64 + ln] / l2;
                stA(inp + (ll)(d0 + kk) * BB + bh * 64 + ln, val);
            }
            if (blk < 16) {
                int bi = tid >> 3, tj = tid & 7;
#pragma unroll
                for (int u = 0; u < 4; ++u) {
                    int tl = tj * 4 + u;
                    p.attnO[((ll)(bh * 64 + bi) * MLEN + s) * TT + jg * 32 + tl] = smu[2048 + tl * 65 + bi];
                }
            }
        }
        gbar(W, ++bar);

        // --- G0: decoder gru layer0 (K=1024: ctx then h0) ---
        {
#pragma unroll
            for (int r = 0; r < 12; ++r) {
                int g = r >> 2, jl = r & 3, j = jg * 4 + jl;
                smu[r * 1024 + tid] = p.dWih0[(ll)(g * HH + j) * 1024 + 512 + tid];
                smu[r * 1024 + 512 + tid] = p.dWhh0[(ll)(g * HH + j) * HH + tid];
            }
            smu[PR_OFF + tid] = 0.0f;
            smu[PR_OFF + 512 + tid] = 0.0f;
            __syncthreads();
            const int ctxw = (wv < 4);
            const float* stream = ctxw ? inp : h0s;
            const int ds0 = (wv & 3) * 128;
            const int tb = ctxw ? 0 : 512;
            float acc[12];
#pragma unroll
            for (int r = 0; r < 12; ++r) acc[r] = 0.0f;
            float av[8];
            for (int c = 0; c < 16; ++c) {
                int db = ds0 + c * 8;
#pragma unroll
                for (int u = 0; u < 8; ++u) av[u] = ldA(stream + (ll)(db + u) * BB + b2);
#pragma unroll
                for (int h2 = 0; h2 < 2; ++h2) {
                    int q4 = (tb + db + h2 * 4) >> 2;
#pragma unroll
                    for (int r = 0; r < 12; ++r) {
                        float4 w = t4[r * 256 + q4];
                        acc[r] = fmaf(w.x, av[h2 * 4 + 0], acc[r]);
                        acc[r] = fmaf(w.y, av[h2 * 4 + 1], acc[r]);
                        acc[r] = fmaf(w.z, av[h2 * 4 + 2], acc[r]);
                        acc[r] = fmaf(w.w, av[h2 * 4 + 3], acc[r]);
                    }
                }
            }
#pragma unroll
            for (int r = 0; r < 12; ++r) {
                int g = r >> 2;
                int prow = (g < 2) ? g * 4 : (ctxw ? 8 : 12);
                unsafeAtomicAdd(&smu[PR_OFF + (prow + (r & 3)) * 64 + lane], acc[r]);
            }
            __syncthreads();
            if (wv < 4) {
                int jl = wv, j = jg * 4 + jl;
                float* pr = smu + PR_OFF;
                int tokb = ldAi(tok + b2);
                float rs = T[(ll)j * 32 + tokb] + pr[(0 + jl) * 64 + lane] + p.dbih0[j] + p.dbhh0[j];
                float zs = T[(ll)(HH + j) * 32 + tokb] + pr[(4 + jl) * 64 + lane] + p.dbih0[HH + j] + p.dbhh0[HH + j];
                float ins = T[(ll)(2 * HH + j) * 32 + tokb] + pr[(8 + jl) * 64 + lane] + p.dbih0[2 * HH + j];
                float hns = pr[(12 + jl) * 64 + lane] + p.dbhh0[2 * HH + j];
                float r = sigf(rs), z = sigf(zs);
                float n = tanhf(ins + r * hns);
                float hp = ldA(h0s + (ll)j * BB + b2);
                stA(g0d + (ll)j * BB + b2, (1.0f - z) * n + z * hp);
            }
        }
        gbar(W, ++bar);

        // --- G1: decoder gru layer1 (K=1024: g0 then h1) ---
        {
#pragma unroll
            for (int r = 0; r < 12; ++r) {
                int g = r >> 2, jl = r & 3, j = jg * 4 + jl;
                smu[r * 1024 + tid] = p.dWih1[(ll)(g * HH + j) * HH + tid];
                smu[r * 1024 + 512 + tid] = p.dWhh1[(ll)(g * HH + j) * HH + tid];
            }
            smu[PR_OFF + tid] = 0.0f;
            smu[PR_OFF + 512 + tid] = 0.0f;
            __syncthreads();
            const int iw = (wv < 4);
            const float* stream = iw ? g0d : h1s;
            const int ds0 = (wv & 3) * 128;
            const int tb = iw ? 0 : 512;
            float acc[12];
#pragma unroll
            for (int r = 0; r < 12; ++r) acc[r] = 0.0f;
            float av[8];
            for (int c = 0; c < 16; ++c) {
                int db = ds0 + c * 8;
#pragma unroll
                for (int u = 0; u < 8; ++u) av[u] = ldA(stream + (ll)(db + u) * BB + b2);
#pragma unroll
                for (int h2 = 0; h2 < 2; ++h2) {
                    int q4 = (tb + db + h2 * 4) >> 2;
#pragma unroll
                    for (int r = 0; r < 12; ++r) {
                        float4 w = t4[r * 256 + q4];
                        acc[r] = fmaf(w.x, av[h2 * 4 + 0], acc[r]);
                        acc[r] = fmaf(w.y, av[h2 * 4 + 1], acc[r]);
                        acc[r] = fmaf(w.z, av[h2 * 4 + 2], acc[r]);
                        acc[r] = fmaf(w.w, av[h2 * 4 + 3], acc[r]);
                    }
                }
            }
#pragma unroll
            for (int r = 0; r < 12; ++r) {
                int g = r >> 2;
                int prow = (g < 2) ? g * 4 : (iw ? 8 : 12);
                unsafeAtomicAdd(&smu[PR_OFF + (prow + (r & 3)) * 64 + lane], acc[r]);
            }
            __syncthreads();
            if (wv < 4) {
                int jl = wv, j = jg * 4 + jl;
                float* pr = smu + PR_OFF;
                float rs = pr[(0 + jl) * 64 + lane] + p.dbih1[j] + p.dbhh1[j];
                float zs = pr[(4 + jl) * 64 + lane] + p.dbih1[HH + j] + p.dbhh1[HH + j];
                float ins = pr[(8 + jl) * 64 + lane] + p.dbih1[2 * HH + j];
                float hns = pr[(12 + jl) * 64 + lane] + p.dbhh1[2 * HH + j];
                float r = sigf(rs), z = sigf(zs);
                float n = tanhf(ins + r * hns);
                float hp = ldA(h1s + (ll)j * BB + b2);
                stA(h1d + (ll)j * BB + b2, (1.0f - z) * n + z * hp);
            }
        }
        gbar(W, ++bar);

        // --- D: query (all blocks) + logits/argmax/tok (blocks 128..135) ---
        {
            const float* h1c = h1d;
            if (tid < 256) smu[PR_OFF + tid] = 0.0f;
            __syncthreads();
            {
                const int ds0 = wv * 64;
                float acc[4] = {0, 0, 0, 0};
                float av[8];
                for (int c = 0; c < 8; ++c) {
                    int db = ds0 + c * 8;
#pragma unroll
                    for (int u = 0; u < 8; ++u) av[u] = ldA(h1c + (ll)(db + u) * BB + b2);
#pragma unroll
                    for (int h2 = 0; h2 < 2; ++h2) {
                        int q4 = (db + h2 * 4) >> 2;
#pragma unroll
                        for (int jl = 0; jl < 4; ++jl) {
                            float4 w = t4q[jl * 128 + q4];
                            acc[jl] = fmaf(w.x, av[h2 * 4 + 0], acc[jl]);
                            acc[jl] = fmaf(w.y, av[h2 * 4 + 1], acc[jl]);
                            acc[jl] = fmaf(w.z, av[h2 * 4 + 2], acc[jl]);
                            acc[jl] = fmaf(w.w, av[h2 * 4 + 3], acc[jl]);
                        }
                    }
                }
#pragma unroll
                for (int jl = 0; jl < 4; ++jl)
                    unsafeAtomicAdd(&smu[PR_OFF + jl * 64 + lane], acc[jl]);
            }
            __syncthreads();
            if (wv < 4) {
                int j = jg * 4 + wv;
                stA(qbm + (ll)j * BB + b2, smu[PR_OFF + wv * 64 + lane] + p.qb[j]);
            }
            if (blk >= 128 && blk < 136) {
                __syncthreads();
                const int bb = (blk - 128) * 16;
                // stage g1 slice [512 d][16 b] into smu[0..8192)
#pragma unroll
                for (int i = 0; i < 16; ++i) {
                    int ff = i * 512 + tid;
                    int d = ff >> 4, bi = ff & 15;
                    smu[ff] = ldA(h1c + (ll)d * BB + bb + bi);
                }
                __syncthreads();
                const int bl = wv * 2 + (lane >> 5);
                const int v = lane & 31;
                float acc = 0.0f;
                for (int d4 = 0; d4 < 128; ++d4) {
                    float4 w4 = *(const float4*)(p.outW + (ll)v * HH + d4 * 4);
                    acc = fmaf(w4.x, smu[(d4 * 4 + 0) * 16 + bl], acc);
                    acc = fmaf(w4.y, smu[(d4 * 4 + 1) * 16 + bl], acc);
                    acc = fmaf(w4.z, smu[(d4 * 4 + 2) * 16 + bl], acc);
                    acc = fmaf(w4.w, smu[(d4 * 4 + 3) * 16 + bl], acc);
                }
                acc += p.outb[v];
                p.vecO[((ll)(bb + bl) * MLEN + s) * VV + v] = acc;
                smu[8704 + wv * 64 + lane] = acc;
                if (v == 0) {
                    int base = 8704 + wv * 64 + (lane >> 5) * 32;
                    float best = smu[base];
                    int bi = 0;
#pragma unroll
                    for (int u = 1; u < 32; ++u) {
                        float val = smu[base + u];
                        if (val > best) { best = val; bi = u; }
                    }
                    stAi(tok + bb + bl, bi);
                }
            }
        }
        gbar(W, ++bar);
    }

    // ================= final hidden [2][128][512] =================
    {
        int idx = blk * 512 + tid;
        int l = idx >> 16, rr = idx & 65535;
        int b = rr >> 9, h = rr & 511;
        const float* src = l ? eh1 : (eh0 + SLOT);
        p.hidO[idx] = ldA(src + (ll)h * BB + b);
    }
}

extern "C" void kernel_launch(void* const* d_in, const int* in_sizes, int n_in,
                              void* d_out, int out_size, void* d_ws, size_t ws_size,
                              hipStream_t stream) {
    (void)in_sizes; (void)n_in; (void)out_size; (void)ws_size;
    P prm;
    prm.x     = (const float*)d_in[0];
    prm.emb   = (const float*)d_in[1];
    prm.eWih0 = (const float*)d_in[2];
    prm.eWhh0 = (const float*)d_in[3];
    prm.ebih0 = (const float*)d_in[4];
    prm.ebhh0 = (const float*)d_in[5];
    prm.eWih1 = (const float*)d_in[6];
    prm.eWhh1 = (const float*)d_in[7];
    prm.ebih1 = (const float*)d_in[8];
    prm.ebhh1 = (const float*)d_in[9];
    prm.dWih0 = (const float*)d_in[10];
    prm.dWhh0 = (const float*)d_in[11];
    prm.dbih0 = (const float*)d_in[12];
    prm.dbhh0 = (const float*)d_in[13];
    prm.dWih1 = (const float*)d_in[14];
    prm.dWhh1 = (const float*)d_in[15];
    prm.dbih1 = (const float*)d_in[16];
    prm.dbhh1 = (const float*)d_in[17];
    prm.qW    = (const float*)d_in[18];
    prm.qb    = (const float*)d_in[19];
    prm.outW  = (const float*)d_in[20];
    prm.outb  = (const float*)d_in[21];
    prm.ws    = (float*)d_ws;
    prm.vecO  = (float*)d_out;
    prm.hidO  = prm.vecO + (ll)BB * MLEN * VV;
    prm.attnO = prm.hidO + (ll)2 * BB * HH;

    hipMemsetAsync(d_ws, 0, 16384, stream);  // barrier gen + tree counters
    void* args[] = { &prm };
    hipLaunchCooperativeKernel((void*)kmain, dim3(256), dim3(512), args, 0, stream);
}